// Round 4
// baseline (650.074 us; speedup 1.0000x reference)
//
#include <hip/hip_runtime.h>
#include <stdint.h>

typedef float v4f __attribute__((ext_vector_type(4)));
typedef short v8s __attribute__((ext_vector_type(8)));

constexpr int Bq = 4, Tq = 8192, Dq = 1024, Fq = 4096;
constexpr int CAP = Tq / 2;     // 4096 tokens selected per batch row
constexpr int Mq  = Bq * CAP;   // 16384 routed tokens total

// ---------- helpers ----------
__device__ __forceinline__ unsigned short f2bf(float f) {
  unsigned int u = __float_as_uint(f);
  u += 0x7FFFu + ((u >> 16) & 1u);   // RNE
  return (unsigned short)(u >> 16);
}

__device__ __forceinline__ void async_cp16(const void* g, void* l) {
  // 16B/lane global->LDS DMA; LDS dest is wave-uniform base + lane*16
  __builtin_amdgcn_global_load_lds(
      (__attribute__((address_space(1))) void*)g,
      (__attribute__((address_space(3))) void*)l, 16, 0, 0);
}

// ---------- scores: s[b,t] = dot(x[b,t,:], w_router), fp64 accumulate ----------
__global__ void scores_kernel(const float* __restrict__ x,
                              const float* __restrict__ wr_g,
                              double* __restrict__ scores) {
  __shared__ __align__(16) float wr[Dq];
  for (int i = threadIdx.x; i < Dq; i += 256) wr[i] = wr_g[i];
  __syncthreads();
  int wid = threadIdx.x >> 6, lane = threadIdx.x & 63;
  int gw = blockIdx.x * 4 + wid;
  const float4* wp = (const float4*)wr;
  for (int rr = 0; rr < 4; ++rr) {
    int row = gw * 4 + rr;   // [0, B*T)
    const float4* xp = (const float4*)(x + (size_t)row * Dq);
    double s = 0.0;
#pragma unroll
    for (int q = 0; q < 4; ++q) {
      float4 v = xp[lane + q * 64];
      float4 w = wp[lane + q * 64];
      s += (double)v.x * w.x + (double)v.y * w.y + (double)v.z * w.z + (double)v.w * w.w;
    }
#pragma unroll
    for (int off = 32; off; off >>= 1) s += __shfl_down(s, off);
    if (lane == 0) scores[row] = s;
  }
}

// ---------- top-k select (exact, per batch row) ----------
__device__ __forceinline__ int block_reduce_i(int v, int* red, int tid) {
#pragma unroll
  for (int off = 32; off; off >>= 1) v += __shfl_down(v, off);
  __syncthreads();                       // protect red[] from previous call
  if ((tid & 63) == 0) red[tid >> 6] = v;
  __syncthreads();
  int s = 0;
#pragma unroll
  for (int k = 0; k < 16; ++k) s += red[k];
  return s;                              // same value in all threads
}

__global__ __launch_bounds__(1024) void select_topk(const double* __restrict__ scores,
                                                    int* __restrict__ selIdx,
                                                    unsigned char* __restrict__ selFlag) {
  int b = blockIdx.x, tid = threadIdx.x;
  const double* s = scores + (size_t)b * Tq;
  __shared__ int red[16];
  __shared__ int counter;
  unsigned long long key[8];
#pragma unroll
  for (int i = 0; i < 8; ++i) {
    unsigned long long u = (unsigned long long)__double_as_longlong(s[tid + i * 1024]);
    key[i] = (u >> 63) ? ~u : (u | 0x8000000000000000ULL);  // order-preserving map
  }
  // cutoff = max X with count(key >= X) >= CAP  (== CAP-th largest key)
  unsigned long long cutoff = 0ULL;
  for (int bit = 63; bit >= 0; --bit) {
    unsigned long long cand = cutoff | (1ULL << bit);
    int c = 0;
#pragma unroll
    for (int i = 0; i < 8; ++i) c += (key[i] >= cand) ? 1 : 0;
    int tot = block_reduce_i(c, red, tid);
    if (tot >= CAP) cutoff = cand;
  }
  int cGt = 0, cEq = 0;
#pragma unroll
  for (int i = 0; i < 8; ++i) { cGt += (key[i] > cutoff); cEq += (key[i] == cutoff); }
  int gtTot = block_reduce_i(cGt, red, tid);
  int eqTot = block_reduce_i(cEq, red, tid);
  int need = CAP - gtTot;                // ties to take (>=1)
  if (tid == 0) counter = 0;
  __syncthreads();
  bool takeAllEq = (eqTot == need);      // common case: no straddling duplicates
#pragma unroll
  for (int i = 0; i < 8; ++i) {
    int t = tid + i * 1024;
    bool sel = takeAllEq ? (key[i] >= cutoff) : (key[i] > cutoff);
    if (sel) { int pos = atomicAdd(&counter, 1); selIdx[b * CAP + pos] = t; }
    selFlag[(size_t)b * Tq + t] = sel ? (unsigned char)1 : (unsigned char)0;
  }
  if (!takeAllEq) {                      // rare: exact ties at cutoff, lowest index first
    __syncthreads();
    if (tid == 0) {
      int taken = 0;
      for (int t = 0; t < Tq && taken < need; ++t) {
        unsigned long long u = (unsigned long long)__double_as_longlong(s[t]);
        unsigned long long k = (u >> 63) ? ~u : (u | 0x8000000000000000ULL);
        if (k == cutoff) {
          selIdx[b * CAP + gtTot + taken] = t;
          selFlag[(size_t)b * Tq + t] = 1;
          ++taken;
        }
      }
    }
  }
}

// ---------- gather selected rows -> bf16 Xs [Mq, Dq] ----------
__global__ void gather_kernel(const float* __restrict__ x,
                              const int* __restrict__ selIdx,
                              unsigned short* __restrict__ Xs) {
  int wid = threadIdx.x >> 6, lane = threadIdx.x & 63;
  int m = blockIdx.x * 4 + wid;          // [0, Mq)
  int b = m >> 12;                       // CAP == 4096
  int tok = selIdx[m];
  const float4* src = (const float4*)(x + ((size_t)b * Tq + tok) * Dq);
  ushort4* dst = (ushort4*)(Xs + (size_t)m * Dq);
#pragma unroll
  for (int q = 0; q < 4; ++q) {
    float4 v = src[lane + q * 64];
    ushort4 o; o.x = f2bf(v.x); o.y = f2bf(v.y); o.z = f2bf(v.z); o.w = f2bf(v.w);
    dst[lane + q * 64] = o;
  }
}

// ---------- pass-through copy of unselected rows ----------
__global__ void copy_pass(const float* __restrict__ x,
                          const unsigned char* __restrict__ selFlag,
                          float* __restrict__ out) {
  int wid = threadIdx.x >> 6, lane = threadIdx.x & 63;
  int row = blockIdx.x * 4 + wid;        // [0, B*T)
  if (selFlag[row]) return;              // wave-uniform branch
  const float4* src = (const float4*)(x + (size_t)row * Dq);
  float4* dst = (float4*)(out + (size_t)row * Dq);
#pragma unroll
  for (int q = 0; q < 4; ++q) dst[lane + q * 64] = src[lane + q * 64];
}

// ---------- fp32 [R,C] -> bf16 transposed [C,R] ----------
__global__ void transpose_f32_to_bf16(const float* __restrict__ in,
                                      unsigned short* __restrict__ out,
                                      int R, int C) {
  __shared__ float tile[32][33];
  int tx = threadIdx.x, ty = threadIdx.y;          // (32, 8)
  int c0 = blockIdx.x * 32, r0 = blockIdx.y * 32;
#pragma unroll
  for (int k = 0; k < 4; ++k)
    tile[ty + k * 8][tx] = in[(size_t)(r0 + ty + k * 8) * C + c0 + tx];
  __syncthreads();
#pragma unroll
  for (int k = 0; k < 4; ++k)
    out[(size_t)(c0 + ty + k * 8) * R + r0 + tx] = f2bf(tile[tx][ty + k * 8]);
}

// ============================================================================
// 256x256-tile, BK=64, 8-wave (2Mx4N), COUNTED-lgkm pipelined phases.
// R3 structural change: phases are (i-half x kk) quadrants; each phase issues
// the NEXT phase's fragment reads (4-8 ds_read_b128) and waits only
// lgkmcnt(8/4) (DS FIFO retirement => previous phase's frags are retired),
// so the LDS unit services reads UNDER the MFMA cluster instead of being
// force-drained before it.  Reads per phase: 8,4,4,8 (balanced).
// Register plan: acc 8x4 v4f (128) + A ping-pong aX/aY (32) + B bfr0/bfr1
// (32, kk-banked; bfr0 read at p3 used p0&p2, bfr1 read p0 used p1&p3).
// Staging (2 gloads/phase, quarter-granular; target region's last reads are
// retired >=1 collective barrier before the stage issues):
//   p0: B-Q2,Q3(t+1)->ot   [B(ot) free since (t-1)p2 barrier]
//   p1: A-Q2,Q3(t+1)->ot   [A-HI(ot) reads retired by (t-1)p3 barrier]
//   p2: A-Q0,Q1(t+2)->bo + vmcnt(2)  [A-LO(bo) retired by p1 barrier]
//   p3: B-Q0,Q1(t+2)->bo   [B(bo) retired by p1 barrier]
// vmcnt(2) at p2 (after issue) completes everything through p1 => tile t+1
// fully resident, collectively guaranteed by p2's barriers before p3's reads.
// Steady state: 10 loads in flight max, drains to 2 once per tile.
// ============================================================================

#define MFMA1(i, j, a, b) acc[i][j] = __builtin_amdgcn_mfma_f32_16x16x32_bf16(a, b, acc[i][j], 0, 0, 0)
#define MMQ16(ib, A, B) do { \
  MFMA1((ib)+0,0,A[0],B[0]); MFMA1((ib)+0,1,A[0],B[1]); MFMA1((ib)+0,2,A[0],B[2]); MFMA1((ib)+0,3,A[0],B[3]); \
  MFMA1((ib)+1,0,A[1],B[0]); MFMA1((ib)+1,1,A[1],B[1]); MFMA1((ib)+1,2,A[1],B[2]); MFMA1((ib)+1,3,A[1],B[3]); \
  MFMA1((ib)+2,0,A[2],B[0]); MFMA1((ib)+2,1,A[2],B[1]); MFMA1((ib)+2,2,A[2],B[2]); MFMA1((ib)+2,3,A[2],B[3]); \
  MFMA1((ib)+3,0,A[3],B[0]); MFMA1((ib)+3,1,A[3],B[1]); MFMA1((ib)+3,2,A[3],B[2]); MFMA1((ib)+3,3,A[3],B[3]); \
} while (0)

// 4 fragment reads: base pointer pre-offset by swizzled lane addr; o0 selects
// i-half (0 = rows 0..63 of the wave tile, 4096 = rows 64..127 equivalents)
#define RD4(dst, p, bo, o0) do { \
  dst[0] = *(const v8s*)((p) + (bo) + (o0));        \
  dst[1] = *(const v8s*)((p) + (bo) + (o0) + 1024); \
  dst[2] = *(const v8s*)((p) + (bo) + (o0) + 2048); \
  dst[3] = *(const v8s*)((p) + (bo) + (o0) + 3072); \
} while (0)

#define STGQ(srcp, qtr, ldst) async_cp16((srcp) + (size_t)(qtr) * 64 * K, (ldst) + (qtr) * 4096)

#define SP1() __builtin_amdgcn_s_setprio(1)
#define SP0() __builtin_amdgcn_s_setprio(0)
#define SB0() __builtin_amdgcn_sched_barrier(0)
#define WAITV(n) asm volatile("s_waitcnt vmcnt(" #n ")" ::: "memory")

// phase boundary: pin; barrier; counted lgkm wait (prev phase's frags retired,
// this phase's stay in flight); pin; prioritized MFMA; pin; barrier.
#define PHW(n, ...) do { \
  SB0(); __builtin_amdgcn_s_barrier(); \
  asm volatile("s_waitcnt lgkmcnt(" #n ")" ::: "memory"); \
  SB0(); \
  SP1(); __VA_ARGS__; SP0(); \
  SB0(); __builtin_amdgcn_s_barrier(); \
} while (0)

// One K-tile (4 phases).  bo/ot = this/other LDS buffer short-offset.
// aN1/bN1 = global src base of tile t+1; aN2/bN2 = tile t+2.
#define TILE4(bo, ot, aN1, bN1, aN2, bN2, S1, S2, WVS, doNext, LG3) do { \
  /* p0: consume (aX=aLO-kk0, bfr0) ; read aLO-kk1 + B-kk1 */ \
  RD4(aY, pA1, bo, 0); RD4(bfr1, pB1, bo, 0); \
  if (S1) { STGQ(bN1, 2, bDst + (ot)); STGQ(bN1, 3, bDst + (ot)); } \
  PHW(8, MMQ16(0, aX, bfr0)); \
  /* p1: consume (aY=aLO-kk1, bfr1) ; read aHI-kk0 */ \
  RD4(aX, pA0, bo, 4096); \
  if (S1) { STGQ(aN1, 2, aDst + (ot)); STGQ(aN1, 3, aDst + (ot)); } \
  PHW(4, MMQ16(0, aY, bfr1)); \
  /* p2: consume (aX=aHI-kk0, bfr0) ; read aHI-kk1 ; residency wait */ \
  RD4(aY, pA1, bo, 4096); \
  if (S2) { STGQ(aN2, 0, aDst + (bo)); STGQ(aN2, 1, aDst + (bo)); } \
  WVS; \
  PHW(4, MMQ16(4, aX, bfr0)); \
  /* p3: consume (aY=aHI-kk1, bfr1) ; read next tile aLO-kk0 + B-kk0 */ \
  if (doNext) { RD4(aX, pA0, ot, 0); RD4(bfr0, pB0, ot, 0); } \
  if (S2) { STGQ(bN2, 0, bDst + (bo)); STGQ(bN2, 1, bDst + (bo)); } \
  PHW(LG3, MMQ16(4, aY, bfr1)); \
} while (0)

template<int K, int NTN, bool IS_G1>
__device__ __forceinline__
void gemm_body(const unsigned short* __restrict__ A,   // [rows, K] bf16
               const unsigned short* __restrict__ Bt,  // [N, K] bf16
               const float* __restrict__ bias,
               unsigned short* __restrict__ Hout,      // IS_G1
               const int* __restrict__ selIdx,         // !IS_G1
               float* __restrict__ out,                // !IS_G1
               int chunkStart) {
  constexpr int NT = K / 64;   // K-tiles (16 or 64)
  __shared__ __align__(16) unsigned short SH[65536];   // 128 KiB
  unsigned short* const As = SH;
  unsigned short* const Bs = SH + 32768;

  const int tid = threadIdx.x;
  const int wid = tid >> 6, lane = tid & 63;
  const int wm = wid >> 2, wn = wid & 3;          // 2 x 4 wave grid
  const int quad = lane >> 4, l16 = lane & 15;

  // bijective XCD swizzle (m204 variant; valid for any grid size)
  const int nwg = gridDim.x;
  const int qq = nwg >> 3, rr = nwg & 7;
  const int xcd = blockIdx.x & 7, loc = blockIdx.x >> 3;
  const int s = (xcd < rr ? xcd * (qq + 1) : rr * (qq + 1) + (xcd - rr) * qq) + loc;
  const int pIdx = s / NTN, nIdx = s % NTN;
  const int m0 = pIdx * 256, n0 = nIdx * 256;

  // ---- staging addressing (pre-swizzled global source, linear LDS dest) ----
  const int sr = tid >> 3;                        // row within 64-row quarter
  const int sc = (tid & 7) ^ (sr & 7);            // swizzled source 16B chunk
  const unsigned short* aSrc = A  + (size_t)(m0 + sr) * K + sc * 8;
  const unsigned short* bSrc = Bt + (size_t)(n0 + sr) * K + sc * 8;
  unsigned short* aDst = As + wid * 512;          // wave-uniform LDS base
  unsigned short* bDst = Bs + wid * 512;

  // ---- read addressing: row*64 + (chunk ^ (row&7))*8 shorts; kk flips bit 5
  const int swz = (quad ^ (l16 & 7)) * 8;
  const int aRdB = (wm * 128 + l16) * 64 + swz;
  const int bRdB = (wn * 64 + l16) * 64 + swz;
  const unsigned short* pA0 = As + aRdB;
  const unsigned short* pA1 = As + (aRdB ^ 32);
  const unsigned short* pB0 = Bs + bRdB;
  const unsigned short* pB1 = Bs + (bRdB ^ 32);

  v4f acc[8][4] = {};
  v8s aX[4], aY[4], bfr0[4], bfr1[4];

  // ---- prologue: tile0 full (8 loads, buf0); tile1 A-Q0,Q1 + B-Q0,Q1 (4, buf1)
  STGQ(aSrc, 0, aDst); STGQ(aSrc, 1, aDst);
  STGQ(bSrc, 0, bDst); STGQ(bSrc, 1, bDst);
  STGQ(aSrc, 2, aDst); STGQ(aSrc, 3, aDst);
  STGQ(bSrc, 2, bDst); STGQ(bSrc, 3, bDst);
  {
    const unsigned short* a1 = aSrc + 64;
    const unsigned short* b1 = bSrc + 64;
    STGQ(a1, 0, aDst + 16384); STGQ(a1, 1, aDst + 16384);
    STGQ(b1, 0, bDst + 16384); STGQ(b1, 1, bDst + 16384);
  }
  WAITV(4);            // tile0's 8 loads done (4 newest may stay in flight)
  SB0(); __builtin_amdgcn_s_barrier(); SB0();
  RD4(aX, pA0, 0, 0); RD4(bfr0, pB0, 0, 0);      // tile0 p0 operands

  // ---- main loop over tile pairs; tail pair peeled ----
  for (int it = 0; it < NT / 2 - 1; ++it) {
    const unsigned short* a1 = aSrc + (size_t)(2 * it + 1) * 64;
    const unsigned short* b1 = bSrc + (size_t)(2 * it + 1) * 64;
    const unsigned short* a2 = aSrc + (size_t)(2 * it + 2) * 64;
    const unsigned short* b2 = bSrc + (size_t)(2 * it + 2) * 64;
    const unsigned short* a3 = aSrc + (size_t)(2 * it + 3) * 64;
    const unsigned short* b3 = bSrc + (size_t)(2 * it + 3) * 64;
    TILE4(0,     16384, a1, b1, a2, b2, true, true, WAITV(2), true, 8);
    TILE4(16384, 0,     a2, b2, a3, b3, true, true, WAITV(2), true, 8);
  }
  { // tiles NT-2 (buf0) and NT-1 (buf1)
    const unsigned short* a1 = aSrc + (size_t)(NT - 1) * 64;
    const unsigned short* b1 = bSrc + (size_t)(NT - 1) * 64;
    TILE4(0,     16384, a1, b1, a1, b1, true,  false, WAITV(0), true,  8);
    TILE4(16384, 0,     a1, b1, a1, b1, false, false, (void)0,  false, 0);
  }

  // ---- epilogue ----
  const int mB = m0 + wm * 128, nB = n0 + wn * 64;
  float bv[4];
#pragma unroll
  for (int j = 0; j < 4; ++j) bv[j] = bias[nB + j * 16 + l16];

  if constexpr (IS_G1) {
    // gelu -> repack full 256x256 bf16 tile through LDS -> coalesced b128 flush
    const float kA = 0.7978845608028654f, kB2 = 0.044715f * 0.7978845608028654f;
    const float kE = -2.0f * 1.4426950408889634f;   // exp(-2z) = exp2(kE*z)
#pragma unroll
    for (int i = 0; i < 8; ++i)
#pragma unroll
      for (int r = 0; r < 4; ++r) {
        const int lrow = wm * 128 + i * 16 + quad * 4 + r;
#pragma unroll
        for (int j = 0; j < 4; ++j) {
          float c = acc[i][j][r] + bv[j];
          float z = c * __builtin_fmaf(kB2, c * c, kA);
          float a = exp2f(kE * fabsf(z));
          float th = copysignf((1.0f - a) * __builtin_amdgcn_rcpf(1.0f + a), z);
          SH[lrow * 256 + wn * 64 + j * 16 + l16] = f2bf(0.5f * c * (1.0f + th));
        }
      }
    __syncthreads();
    // flush: thread t handles row t>>1, 128-col half t&1 (256 B contiguous)
    {
      const int row = tid >> 1, half = tid & 1;
      const unsigned short* sp = SH + row * 256 + half * 128;
      unsigned short* dp = Hout + (size_t)(m0 + row) * Fq + n0 + half * 128;
#pragma unroll
      for (int c = 0; c < 16; ++c)
        *(v8s*)(dp + c * 8) = *(const v8s*)(sp + c * 8);
    }
  } else {
#pragma unroll
    for (int i = 0; i < 8; ++i)
#pragma unroll
      for (int r = 0; r < 4; ++r) {
        const int lrow = mB + i * 16 + quad * 4 + r;
        const int m = chunkStart + lrow;
        const int b = m >> 12;             // CAP == 4096
        const int tok = selIdx[m];
        float* op = out + ((size_t)b * Tq + tok) * Dq;
#pragma unroll
        for (int j = 0; j < 4; ++j)
          op[nB + j * 16 + l16] = acc[i][j][r] + bv[j];
      }
  }
}

__global__ __launch_bounds__(512, 2)
void g1_ffn_gelu(const unsigned short* __restrict__ A,
                 const unsigned short* __restrict__ Bt,
                 const float* __restrict__ bias,
                 unsigned short* __restrict__ Hout) {
  gemm_body<Dq, Fq / 256, true>(A, Bt, bias, Hout, nullptr, nullptr, 0);
}

__global__ __launch_bounds__(512, 2)
void g2_out_scatter(const unsigned short* __restrict__ A,
                    const unsigned short* __restrict__ Bt,
                    const float* __restrict__ bias,
                    const int* __restrict__ selIdx,
                    float* __restrict__ out,
                    int chunkStart) {
  gemm_body<Fq, Dq / 256, false>(A, Bt, bias, nullptr, selIdx, out, chunkStart);
}

// ---------- host ----------
extern "C" void kernel_launch(void* const* d_in, const int* in_sizes, int n_in,
                              void* d_out, int out_size, void* d_ws, size_t ws_size,
                              hipStream_t stream) {
  const float* x        = (const float*)d_in[0];
  const float* w_router = (const float*)d_in[1];
  const float* w1       = (const float*)d_in[2];
  const float* b1       = (const float*)d_in[3];
  const float* w2       = (const float*)d_in[4];
  const float* b2       = (const float*)d_in[5];
  float* out = (float*)d_out;

  char* p = (char*)d_ws;
  auto alloc = [&](size_t bytes) {
    char* r = p;
    p += (bytes + 255) & ~(size_t)255;
    return r;
  };
  double* scores          = (double*)alloc((size_t)Bq * Tq * 8);
  int* selIdx             = (int*)alloc((size_t)Mq * 4);
  unsigned char* selFlag  = (unsigned char*)alloc((size_t)Bq * Tq);
  unsigned short* W1t     = (unsigned short*)alloc((size_t)Dq * Fq * 2);  // [F, D]
  unsigned short* W2t     = (unsigned short*)alloc((size_t)Dq * Fq * 2);  // [D, F]
  unsigned short* Xs      = (unsigned short*)alloc((size_t)Mq * Dq * 2);  // [M, D]
  size_t used = (size_t)(p - (char*)d_ws);
  size_t rem = ws_size > used ? ws_size - used : 0;
  int chunkRows = (int)(rem / ((size_t)Fq * 2));
  chunkRows = (chunkRows / 256) * 256;
  if (chunkRows > Mq) chunkRows = Mq;
  if (chunkRows < 256) chunkRows = 256;   // requires ws_size >= ~51 MB
  unsigned short* H = (unsigned short*)p;  // [chunkRows, F] bf16

  transpose_f32_to_bf16<<<dim3(Fq / 32, Dq / 32), dim3(32, 8), 0, stream>>>(w1, W1t, Dq, Fq);
  transpose_f32_to_bf16<<<dim3(Dq / 32, Fq / 32), dim3(32, 8), 0, stream>>>(w2, W2t, Fq, Dq);
  scores_kernel<<<2048, 256, 0, stream>>>(x, w_router, scores);
  select_topk<<<Bq, 1024, 0, stream>>>(scores, selIdx, selFlag);
  gather_kernel<<<Mq / 4, 256, 0, stream>>>(x, selIdx, Xs);
  copy_pass<<<(Bq * Tq) / 4, 256, 0, stream>>>(x, selFlag, out);

  for (int r0 = 0; r0 < Mq; r0 += chunkRows) {
    int rows = (Mq - r0 < chunkRows) ? (Mq - r0) : chunkRows;
    int p1 = rows / 256;
    g1_ffn_gelu<<<p1 * (Fq / 256), 512, 0, stream>>>(Xs + (size_t)r0 * Dq, W1t, b1, H);
    g2_out_scatter<<<p1 * (Dq / 256), 512, 0, stream>>>(H, W2t, b2, selIdx, out, r0);
  }
}